// Round 2
// baseline (292935.522 us; speedup 1.0000x reference)
//
#include <hip/hip_runtime.h>
#include <hip/hip_bf16.h>

#define RNNU 400
#define NBATCH 256
#define TT 800
#define UU 100
#define ALW 80
#define KW 10
#define K1 416
#define K2 896
#define NBLK 256
#define NTHR 256

typedef unsigned short u16;
typedef unsigned int u32;
typedef __attribute__((ext_vector_type(8))) short bfrag;   // 8 bf16
typedef __attribute__((ext_vector_type(4))) float f4;

// plane sizes (elements)
constexpr long P1 = (long)NBATCH * K1;      // 106496
constexpr long P2 = (long)NBATCH * K2;      // 229376
constexpr long WP1 = 1600L * K1;            // 665600
constexpr long WP2 = 1600L * K2;            // 1433600
constexpr long WPM = 128L * K1;             // 53248
constexpr long WPW = 32L * K1;              // 13312

// ---------------- workspace layout (bytes) ----------------
constexpr size_t OFF_FLAGS = 0;                                    // 4096 u32
constexpr size_t OFF_U1 = 16384;                                   // 2 dbuf x 2 planes
constexpr size_t OFF_U2 = OFF_U1 + (size_t)4 * P1 * 2;
constexpr size_t OFF_U3 = OFF_U2 + (size_t)4 * P2 * 2;
constexpr size_t OFF_W1 = OFF_U3 + (size_t)4 * P2 * 2;             // 2 planes
constexpr size_t OFF_W2 = OFF_W1 + (size_t)2 * WP1 * 2;
constexpr size_t OFF_W3 = OFF_W2 + (size_t)2 * WP2 * 2;
constexpr size_t OFF_WM = OFF_W3 + (size_t)2 * WP2 * 2;
constexpr size_t OFF_WW = OFF_WM + (size_t)2 * WPM * 2;
constexpr size_t OFF_PB1 = OFF_WW + (size_t)2 * WPW * 2;           // 1600 f32
constexpr size_t OFF_PB2 = OFF_PB1 + 6400;
constexpr size_t OFF_PB3 = OFF_PB2 + 6400;
constexpr size_t OFF_C1 = OFF_PB3 + 6400;                          // 256*400 f32 each
constexpr size_t OFF_C2 = OFF_C1 + 409600;
constexpr size_t OFF_C3 = OFF_C2 + 409600;
constexpr size_t OFF_KP = OFF_C3 + 409600;                         // 2560 f32

__device__ __forceinline__ u16 f2b(float x) {
  union { float f; u32 u; } v; v.f = x;
  u32 r = (v.u + 0x7FFFu + ((v.u >> 16) & 1u)) >> 16;
  return (u16)r;
}
__device__ __forceinline__ float b2f(u16 h) {
  union { u32 u; float f; } q; q.u = ((u32)h) << 16; return q.f;
}
// write split hi/lo bf16 planes
__device__ __forceinline__ void wsp2(u16* base, long plane, long idx, float v) {
  u16 hi = f2b(v);
  base[idx] = hi;
  base[plane + idx] = f2b(v - b2f(hi));
}
__device__ __forceinline__ float sigf(float x) { return 1.f / (1.f + __expf(-x)); }
__device__ __forceinline__ float tanhf_(float x) {
  float e = __expf(-2.f * x); return (1.f - e) / (1.f + e);
}

// ---------------- prep: weight convert (split planes) + state init ----------------
__global__ void prep_kernel(
    const float* __restrict__ w_ih1, const float* __restrict__ w_hh1, const float* __restrict__ b1,
    const float* __restrict__ w_ih2, const float* __restrict__ w_hh2, const float* __restrict__ b2,
    const float* __restrict__ w_ih3, const float* __restrict__ w_hh3, const float* __restrict__ b3,
    const float* __restrict__ w_win, const float* __restrict__ w_mdn,
    const float* __restrict__ traj, char* __restrict__ ws)
{
  u16* W1 = (u16*)(ws + OFF_W1);
  u16* W2 = (u16*)(ws + OFF_W2);
  u16* W3 = (u16*)(ws + OFF_W3);
  u16* WM = (u16*)(ws + OFF_WM);
  u16* WW = (u16*)(ws + OFF_WW);

  const long N1 = WP1, N2 = WP2, N3 = WP2;
  const long N4 = WPM, N5 = WPW, N6 = 4800, N7 = 307200, N8 = 2560, N9 = 4096;
  const long N10 = P1, N11 = (long)NBATCH * RNNU, N12 = (long)NBATCH * RNNU;
  const long total = N1 + N2 + N3 + N4 + N5 + N6 + N7 + N8 + N9 + N10 + N11 + N12;

  for (long i = (long)blockIdx.x * blockDim.x + threadIdx.x; i < total;
       i += (long)gridDim.x * blockDim.x) {
    long j = i;
    if (j < N1) { int n = (int)(j / K1), k = (int)(j % K1);
      int s = (n & 3) * 400 + (n >> 2);
      float v = (k < 3) ? w_ih1[s * 3 + k] : ((k >= 16) ? w_hh1[(long)s * 400 + (k - 16)] : 0.f);
      wsp2(W1, WP1, j, v); continue; } j -= N1;
    if (j < N2) { int n = (int)(j / K2), k = (int)(j % K2);
      int s = (n & 3) * 400 + (n >> 2);
      float v = (k < 483) ? w_ih2[(long)s * 483 + k] : ((k >= 496) ? w_hh2[(long)s * 400 + (k - 496)] : 0.f);
      wsp2(W2, WP2, j, v); continue; } j -= N2;
    if (j < N3) { int n = (int)(j / K2), k = (int)(j % K2);
      int s = (n & 3) * 400 + (n >> 2);
      float v = (k < 483) ? w_ih3[(long)s * 483 + k] : ((k >= 496) ? w_hh3[(long)s * 400 + (k - 496)] : 0.f);
      wsp2(W3, WP2, j, v); continue; } j -= N3;
    if (j < N4) { int n = (int)(j / K1), k = (int)(j % K1);
      float v = (n < 121 && k >= 16) ? w_mdn[(long)n * 400 + (k - 16)] : 0.f;
      wsp2(WM, WPM, j, v); continue; } j -= N4;
    if (j < N5) { int n = (int)(j / K1), k = (int)(j % K1);
      float v = (n < 30 && k < 400) ? w_win[(long)n * 400 + k] : 0.f;
      wsp2(WW, WPW, j, v); continue; } j -= N5;
    if (j < N6) { int w = (int)(j / 1600), n = (int)(j % 1600);
      int s = (n & 3) * 400 + (n >> 2);
      float* pb = (float*)(ws + (w == 0 ? OFF_PB1 : (w == 1 ? OFF_PB2 : OFF_PB3)));
      const float* bb = (w == 0 ? b1 : (w == 1 ? b2 : b3));
      pb[n] = bb[s]; continue; } j -= N6;
    if (j < N7) { ((float*)(ws + OFF_C1))[j] = 0.f; continue; } j -= N7;   // c1,c2,c3 contiguous
    if (j < N8) { ((float*)(ws + OFF_KP))[j] = 0.f; continue; } j -= N8;
    if (j < N9) { ((u32*)(ws + OFF_FLAGS))[j] = 0u; continue; } j -= N9;
    if (j < N10) { int r = (int)(j / K1), k = (int)(j % K1);
      u16* U1 = (u16*)(ws + OFF_U1);
      float v = (k < 3) ? traj[(long)r * 2400 + k] : 0.f;   // t=0 x + zero h1/pad
      wsp2(U1, P1, j, v); continue; } j -= N10;
    if (j < N11) { int r = (int)(j / 400), k = (int)(j % 400);
      u16* U2 = (u16*)(ws + OFF_U2);
      long idx = (long)r * K2 + 496 + k;
      U2[idx] = 0; U2[P2 + idx] = 0; continue; } j -= N11;
    { int r = (int)(j / 400), k = (int)(j % 400);
      u16* U3 = (u16*)(ws + OFF_U3);
      long idx = (long)r * K2 + 496 + k;
      U3[idx] = 0; U3[P2 + idx] = 0; }
  }
}

// ---------------- grid barrier: per-block flag, all threads poll ----------------
__device__ __forceinline__ void gridbar(u32* flags, u32 e, int bid, int tid) {
  __syncthreads();
  if (tid == 0) {
    __threadfence();
    __hip_atomic_store(&flags[bid * 16], e, __ATOMIC_RELEASE, __HIP_MEMORY_SCOPE_AGENT);
  }
  u32* f = &flags[tid * 16];
  while (__hip_atomic_load(f, __ATOMIC_RELAXED, __HIP_MEMORY_SCOPE_AGENT) < e) {
    __builtin_amdgcn_s_sleep(1);
  }
  __threadfence();
  __syncthreads();
}

// ---------------- GEMM tile (32 rows x 80 cols), 3-pass split-bf16, fused LSTM cell ----------------
template<int NK, int KPAD>
__device__ __forceinline__ void gemm_gate_tile(
    int rt, int ct, const u16* __restrict__ Abase, long APS,
    const u16* __restrict__ Wbase, long WPS,
    const float* __restrict__ pbias, float* __restrict__ cst,
    u16* __restrict__ hd0, int st0, long ps0,
    u16* __restrict__ hd1, int st1, long ps1,
    float* __restrict__ ldsb, int lane)
{
  const int r0 = rt * 32, c0 = ct * 80;
  f4 acc[2][5];
#pragma unroll
  for (int a = 0; a < 2; a++)
#pragma unroll
    for (int b = 0; b < 5; b++) acc[a][b] = (f4)(0.f);

  const long aoff = (long)(r0 + (lane & 15)) * KPAD + ((lane >> 4) * 8);
  const long woff = (long)(c0 + (lane & 15)) * KPAD + ((lane >> 4) * 8);

#pragma unroll 1
  for (int pass = 0; pass < 3; ++pass) {
    const u16* Ap0 = Abase + ((pass == 2) ? APS : 0) + aoff;
    const u16* Ap1 = Ap0 + 16 * KPAD;
    const u16* Wp  = Wbase + ((pass == 1) ? WPS : 0) + woff;
#pragma unroll
    for (int kb = 0; kb < NK; ++kb) {
      bfrag a0 = *(const bfrag*)(Ap0 + kb * 32);
      bfrag a1 = *(const bfrag*)(Ap1 + kb * 32);
#pragma unroll
      for (int cf = 0; cf < 5; ++cf) {
        bfrag bf = *(const bfrag*)(Wp + (long)cf * 16 * KPAD + kb * 32);
        acc[0][cf] = __builtin_amdgcn_mfma_f32_16x16x32_bf16(a0, bf, acc[0][cf], 0, 0, 0);
        acc[1][cf] = __builtin_amdgcn_mfma_f32_16x16x32_bf16(a1, bf, acc[1][cf], 0, 0, 0);
      }
    }
  }
  // dump (+bias) to LDS, then per-(row,unit) LSTM cell
  const int cl = lane & 15, rq = lane >> 4;
#pragma unroll
  for (int rf = 0; rf < 2; ++rf)
#pragma unroll
    for (int cf = 0; cf < 5; ++cf) {
      float bias = pbias[c0 + cf * 16 + cl];
#pragma unroll
      for (int r = 0; r < 4; ++r)
        ldsb[(rf * 16 + rq * 4 + r) * 80 + cf * 16 + cl] = acc[rf][cf][r] + bias;
    }
  asm volatile("s_waitcnt lgkmcnt(0)" ::: "memory");
#pragma unroll
  for (int q = 0; q < 10; ++q) {
    int idx = q * 64 + lane;
    int rl = idx / 20, ul = idx % 20;
    float gi = ldsb[rl * 80 + 4 * ul + 0];
    float gf = ldsb[rl * 80 + 4 * ul + 1];
    float gg = ldsb[rl * 80 + 4 * ul + 2];
    float go = ldsb[rl * 80 + 4 * ul + 3];
    long row = r0 + rl; int unit = ct * 20 + ul;
    long ci = row * 400 + unit;
    float cn = sigf(gf) * cst[ci] + sigf(gi) * tanhf_(gg);
    cst[ci] = cn;
    float hv = sigf(go) * tanhf_(cn);
    u16 hh = f2b(hv);
    u16 hl = f2b(hv - b2f(hh));
    long i0 = row * st0 + unit;
    hd0[i0] = hh; hd0[ps0 + i0] = hl;
    if (hd1) { long i1 = row * st1 + unit; hd1[i1] = hh; hd1[ps1 + i1] = hl; }
  }
}

// ---------------- MDN head tile (16 rows x 128 cols, K=416 @ col-offset 480) ----------------
__device__ __forceinline__ void mdn_tile(
    int mt, const u16* __restrict__ Abase, long APS,
    const u16* __restrict__ Wm, long WPS,
    const float* __restrict__ b_mdn, float* __restrict__ out, int tcol, int lane)
{
  const int r0 = mt * 16;
  f4 acc[8];
#pragma unroll
  for (int c = 0; c < 8; c++) acc[c] = (f4)(0.f);
  const long aoff = (long)(r0 + (lane & 15)) * K2 + ((lane >> 4) * 8);
  const long woff = (long)(lane & 15) * K1 + ((lane >> 4) * 8);
#pragma unroll 1
  for (int pass = 0; pass < 3; ++pass) {
    const u16* Ap = Abase + ((pass == 2) ? APS : 0) + aoff;
    const u16* Wp = Wm + ((pass == 1) ? WPS : 0) + woff;
#pragma unroll
    for (int kb = 0; kb < 13; ++kb) {
      bfrag a = *(const bfrag*)(Ap + kb * 32);
#pragma unroll
      for (int cf = 0; cf < 8; ++cf) {
        bfrag b = *(const bfrag*)(Wp + (long)cf * 16 * K1 + kb * 32);
        acc[cf] = __builtin_amdgcn_mfma_f32_16x16x32_bf16(a, b, acc[cf], 0, 0, 0);
      }
    }
  }
  const int cl = lane & 15, rq = lane >> 4;
#pragma unroll
  for (int cf = 0; cf < 8; ++cf) {
    int col = cf * 16 + cl;
    if (col < 121) {
      float bias = b_mdn[col];
#pragma unroll
      for (int r = 0; r < 4; ++r) {
        long row = r0 + rq * 4 + r;
        out[(row * TT + tcol) * 121 + col] = acc[cf][r] + bias;
      }
    }
  }
}

// ---------------- persistent kernel ----------------
__global__ void __launch_bounds__(NTHR) handw_kernel(
    const float* __restrict__ traj, const float* __restrict__ chars,
    const float* __restrict__ b_win, const float* __restrict__ b_mdn,
    float* __restrict__ out, char* __restrict__ ws)
{
  u32* flags = (u32*)(ws + OFF_FLAGS);
  u16* U1b = (u16*)(ws + OFF_U1);
  u16* U2b = (u16*)(ws + OFF_U2);
  u16* U3b = (u16*)(ws + OFF_U3);
  const u16* W1 = (const u16*)(ws + OFF_W1);
  const u16* W2 = (const u16*)(ws + OFF_W2);
  const u16* W3 = (const u16*)(ws + OFF_W3);
  const u16* WM = (const u16*)(ws + OFF_WM);
  const u16* WW = (const u16*)(ws + OFF_WW);
  const float* PB1 = (const float*)(ws + OFF_PB1);
  const float* PB2 = (const float*)(ws + OFF_PB2);
  const float* PB3 = (const float*)(ws + OFF_PB3);
  float* C1 = (float*)(ws + OFF_C1);
  float* C2 = (float*)(ws + OFF_C2);
  float* C3 = (float*)(ws + OFF_C3);
  float* KP = (float*)(ws + OFF_KP);

  __shared__ float ldseb[2][32 * 80];
  __shared__ float ldswp[16 * 32];
  __shared__ float ldsal[16 * KW];
  __shared__ float ldsbe[16 * KW];
  __shared__ float ldskp[16 * KW];
  __shared__ float ldsphi[16 * UU];

  const int bid = blockIdx.x, tid = threadIdx.x;
  const int wid = tid >> 6, lane = tid & 63;
  u32 epoch = 0;
  const int gtile = (wid < 2 && bid < 80) ? (wid * 80 + bid) : -1;
  const int rt = (gtile >= 0) ? gtile / 20 : 0;
  const int ct = (gtile >= 0) ? gtile % 20 : 0;

  for (int t = 0; t < TT; ++t) {
    const int p = t & 1;
    u16* U1p = U1b + (size_t)p * 2 * P1;
    u16* U1n = U1b + (size_t)(p ^ 1) * 2 * P1;
    u16* U2p = U2b + (size_t)p * 2 * P2;
    u16* U2n = U2b + (size_t)(p ^ 1) * 2 * P2;
    u16* U3p = U3b + (size_t)p * 2 * P2;
    u16* U3n = U3b + (size_t)(p ^ 1) * 2 * P2;

    // ---- Phase A: gates1 (K=416) -> h1,c1 ; MDN for t-1 ----
    if (gtile >= 0)
      gemm_gate_tile<13, K1>(rt, ct, U1p, P1, W1, WP1, PB1, C1,
                             U1n + 16, K1, P1, U2p, K2, P2, ldseb[wid], lane);
    if (t > 0 && wid == 0 && bid >= 80 && bid < 96)
      mdn_tile(bid - 80, U3p + 480, P2, WM, WPM, b_mdn, out, t - 1, lane);
    gridbar(flags, ++epoch, bid, tid);

    // ---- Phase B: window params + kappa/phi/window + x writes ----
    if (bid < 16) {
      const int r0 = bid * 16;
      if (wid == 0) {
        f4 wacc[2]; wacc[0] = (f4)(0.f); wacc[1] = (f4)(0.f);
        const long aoff = (long)(r0 + (lane & 15)) * K2 + ((lane >> 4) * 8);
        const long woff = (long)(lane & 15) * K1 + ((lane >> 4) * 8);
#pragma unroll 1
        for (int pass = 0; pass < 3; ++pass) {
          const u16* Ap = U2p + ((pass == 2) ? P2 : 0) + aoff;
          const u16* Wp = WW + ((pass == 1) ? WPW : 0) + woff;
#pragma unroll
          for (int kb = 0; kb < 13; ++kb) {
            bfrag a = *(const bfrag*)(Ap + kb * 32);
            bfrag b0 = *(const bfrag*)(Wp + kb * 32);
            bfrag b1 = *(const bfrag*)(Wp + 16 * K1 + kb * 32);
            wacc[0] = __builtin_amdgcn_mfma_f32_16x16x32_bf16(a, b0, wacc[0], 0, 0, 0);
            wacc[1] = __builtin_amdgcn_mfma_f32_16x16x32_bf16(a, b1, wacc[1], 0, 0, 0);
          }
        }
        const int cl = lane & 15, rq = lane >> 4;
#pragma unroll
        for (int cf = 0; cf < 2; ++cf) {
          int col = cf * 16 + cl;
          float bias = (col < 30) ? b_win[col] : 0.f;
#pragma unroll
          for (int r = 0; r < 4; ++r)
            ldswp[(rq * 4 + r) * 32 + col] = wacc[cf][r] + bias;
        }
      }
      __syncthreads();
      if (tid < 160) {
        int r = tid / 10, k = tid % 10; int row = r0 + r;
        float kap = KP[row * 10 + k] + __expf(ldswp[r * 32 + 20 + k]);
        KP[row * 10 + k] = kap;
        ldskp[r * 10 + k] = kap;
        ldsal[r * 10 + k] = __expf(ldswp[r * 32 + k]);
        ldsbe[r * 10 + k] = __expf(ldswp[r * 32 + 10 + k]);
      } else if (tid < 208) {
        int q = tid - 160; int r = q / 3, c = q % 3; int row = r0 + r;
        float xv = traj[((long)row * TT + t) * 3 + c];
        wsp2(U2p, P2, (long)row * K2 + 480 + c, xv);
        wsp2(U3p, P2, (long)row * K2 + 480 + c, xv);
        if (t + 1 < TT)
          wsp2(U1n, P1, (long)row * K1 + c, traj[((long)row * TT + t + 1) * 3 + c]);
      }
      __syncthreads();
      {
        int r = tid & 15, uq = tid >> 4;
        for (int u = uq; u < UU; u += 16) {
          float s = 0.f;
#pragma unroll
          for (int k = 0; k < KW; ++k) {
            float d = ldskp[r * 10 + k] - (float)u;
            s += ldsal[r * 10 + k] * __expf(-ldsbe[r * 10 + k] * d * d);
          }
          ldsphi[r * UU + u] = s;
        }
      }
      __syncthreads();
      {
        int r = tid >> 4, d0 = tid & 15; int row = r0 + r;
        float w[5] = {0.f, 0.f, 0.f, 0.f, 0.f};
        const float* cb = chars + (long)row * UU * ALW;
        for (int u = 0; u < UU; ++u) {
          float ph = ldsphi[r * UU + u];
#pragma unroll
          for (int jj = 0; jj < 5; ++jj) w[jj] += ph * cb[u * ALW + d0 + 16 * jj];
        }
#pragma unroll
        for (int jj = 0; jj < 5; ++jj) {
          int d = d0 + 16 * jj;
          wsp2(U2p, P2, (long)row * K2 + 400 + d, w[jj]);
          wsp2(U3p, P2, (long)row * K2 + 400 + d, w[jj]);
        }
      }
    }
    gridbar(flags, ++epoch, bid, tid);

    // ---- Phase C: gates2 (K=896) -> h2,c2 ----
    if (gtile >= 0)
      gemm_gate_tile<28, K2>(rt, ct, U2p, P2, W2, WP2, PB2, C2,
                             U3p, K2, P2, U2n + 496, K2, P2, ldseb[wid], lane);
    gridbar(flags, ++epoch, bid, tid);

    // ---- Phase D: gates3 (K=896) -> h3,c3 ----
    if (gtile >= 0)
      gemm_gate_tile<28, K2>(rt, ct, U3p, P2, W3, WP2, PB3, C3,
                             U3n + 496, K2, P2, (u16*)nullptr, 0, 0, ldseb[wid], lane);
    gridbar(flags, ++epoch, bid, tid);
  }
  // final MDN output for t = TT-1 (h3 lives in U3 buffer 0 h-slot)
  if (wid == 0 && bid >= 80 && bid < 96)
    mdn_tile(bid - 80, U3b + 480, P2, WM, WPM, b_mdn, out, TT - 1, lane);
}

// ---------------- host entry ----------------
extern "C" void kernel_launch(void* const* d_in, const int* in_sizes, int n_in,
                              void* d_out, int out_size, void* d_ws, size_t ws_size,
                              hipStream_t stream) {
  const float* traj   = (const float*)d_in[0];
  const float* chars  = (const float*)d_in[1];
  const float* w_ih1  = (const float*)d_in[2];
  const float* w_hh1  = (const float*)d_in[3];
  const float* b1     = (const float*)d_in[4];
  const float* w_ih2  = (const float*)d_in[5];
  const float* w_hh2  = (const float*)d_in[6];
  const float* b2     = (const float*)d_in[7];
  const float* w_ih3  = (const float*)d_in[8];
  const float* w_hh3  = (const float*)d_in[9];
  const float* b3     = (const float*)d_in[10];
  const float* w_win  = (const float*)d_in[11];
  const float* b_win  = (const float*)d_in[12];
  const float* w_mdn  = (const float*)d_in[13];
  const float* b_mdn  = (const float*)d_in[14];
  float* outp = (float*)d_out;
  char* wsp = (char*)d_ws;

  prep_kernel<<<dim3(8192), dim3(256), 0, stream>>>(
      w_ih1, w_hh1, b1, w_ih2, w_hh2, b2, w_ih3, w_hh3, b3, w_win, w_mdn, traj, wsp);

  void* kargs[] = { (void*)&traj, (void*)&chars, (void*)&b_win, (void*)&b_mdn,
                    (void*)&outp, (void*)&wsp };
  hipError_t err = hipLaunchCooperativeKernel((void*)handw_kernel, dim3(NBLK), dim3(NTHR),
                                              kargs, 0, stream);
  if (err != hipSuccess) {
    // fallback: plain launch (256 blocks of 256 threads trivially co-resident on 256 CUs)
    handw_kernel<<<dim3(NBLK), dim3(NTHR), 0, stream>>>(traj, chars, b_win, b_mdn, outp, wsp);
  }
}